// Round 1
// baseline (212.368 us; speedup 1.0000x reference)
//
#include <hip/hip_runtime.h>

typedef unsigned short u16;
typedef __attribute__((ext_vector_type(8))) __bf16 bf16x8;
typedef __attribute__((ext_vector_type(4))) float f32x4;
typedef __attribute__((ext_vector_type(8))) u16 u16x8;

#define MFMA(a, b, c) __builtin_amdgcn_mfma_f32_16x16x32_bf16((a), (b), (c), 0, 0, 0)

// B=2, T=2048, H=1024, NH=16, HD=64, WINDOW=256
#define TT 2048
#define NHEAD 16
#define HDIM 64

__device__ __forceinline__ u16 f2bf(float f) {
  union { float f; unsigned u; } v; v.f = f;
  unsigned r = (v.u + 0x7fffu + ((v.u >> 16) & 1u)) >> 16;
  return (u16)r;
}

__device__ __forceinline__ void gll16(const u16* g, u16* l) {
  __builtin_amdgcn_global_load_lds(
      (__attribute__((address_space(1))) void*)g,
      (__attribute__((address_space(3))) void*)l, 16, 0, 0);
}

// ---------------- f32 -> bf16 convert (x) ----------------
__global__ __launch_bounds__(256) void cvt_bf16_k(const float* __restrict__ in,
                                                  u16* __restrict__ out) {
  int i = blockIdx.x * 256 + threadIdx.x;  // one thread = 8 elems
  float4 a = ((const float4*)in)[2 * i];
  float4 b = ((const float4*)in)[2 * i + 1];
  u16x8 r;
  r[0] = f2bf(a.x); r[1] = f2bf(a.y); r[2] = f2bf(a.z); r[3] = f2bf(a.w);
  r[4] = f2bf(b.x); r[5] = f2bf(b.y); r[6] = f2bf(b.z); r[7] = f2bf(b.w);
  ((u16x8*)out)[i] = r;
}

// ---------------- transpose + convert: in[R][C] f32 -> out[C][R] bf16 ----------------
__global__ __launch_bounds__(256) void transpose_cvt_k(const float* __restrict__ in,
                                                       u16* __restrict__ out,
                                                       int R, int C) {
  __shared__ float tile[32][33];
  int tx = threadIdx.x & 31, ty = threadIdx.x >> 5;  // 32 x 8
  int r0 = blockIdx.y * 32, c0 = blockIdx.x * 32;
#pragma unroll
  for (int i = 0; i < 4; ++i)
    tile[ty + i * 8][tx] = in[(size_t)(r0 + ty + i * 8) * C + c0 + tx];
  __syncthreads();
#pragma unroll
  for (int i = 0; i < 4; ++i)
    out[(size_t)(c0 + ty + i * 8) * R + r0 + tx] = f2bf(tile[tx][ty + i * 8]);
}

// ---------------- GEMM core: C[128x128] += A[128xK] * Bt[128xK]^T, K=1024 ----------------
// A row-major [M][1024] bf16, Bt row-major [N][1024] bf16 (i.e. B transposed).
// 256 threads = 4 waves in 2x2; each wave does 64x64 via 4x4 16x16x32 MFMA frags.
__device__ __forceinline__ void gemm_core(const u16* __restrict__ A,
                                          const u16* __restrict__ Bt,
                                          int m0, int n0,
                                          u16* As, u16* Bs, f32x4 acc[4][4]) {
  const int tid = threadIdx.x;
  const int w = tid >> 6, lane = tid & 63;
  const int wr = w >> 1, wc = w & 1;
  const int lr = lane & 15, lk = (lane >> 4) << 3;
  const int srow = w << 5;  // each wave stages 32 rows of each tile
  const u16* ga = A + (size_t)(m0 + srow + (lane >> 3)) * 1024 + ((lane & 7) << 3);
  const u16* gb = Bt + (size_t)(n0 + srow + (lane >> 3)) * 1024 + ((lane & 7) << 3);
  u16* la = As + srow * 64;
  u16* lb = Bs + srow * 64;
  for (int k0 = 0; k0 < 1024; k0 += 64) {
#pragma unroll
    for (int i = 0; i < 4; ++i) {
      gll16(ga + i * 8192 + k0, la + i * 512);
      gll16(gb + i * 8192 + k0, lb + i * 512);
    }
    __syncthreads();
#pragma unroll
    for (int kk = 0; kk < 64; kk += 32) {
      bf16x8 af[4], bfr[4];
#pragma unroll
      for (int m = 0; m < 4; ++m)
        af[m] = *(const bf16x8*)(As + ((wr << 6) + m * 16 + lr) * 64 + kk + lk);
#pragma unroll
      for (int n = 0; n < 4; ++n)
        bfr[n] = *(const bf16x8*)(Bs + ((wc << 6) + n * 16 + lr) * 64 + kk + lk);
#pragma unroll
      for (int m = 0; m < 4; ++m)
#pragma unroll
        for (int n = 0; n < 4; ++n)
          acc[m][n] = MFMA(af[m], bfr[n], acc[m][n]);
    }
    __syncthreads();
  }
}

// ---------------- GEMM1: qkv = x @ Wqkv + b, scatter to q/k/vT bf16 ----------------
__global__ __launch_bounds__(256) void gemm_qkv_k(const u16* __restrict__ A,
                                                  const u16* __restrict__ Bt,
                                                  const float* __restrict__ bias,
                                                  u16* __restrict__ qo,
                                                  u16* __restrict__ ko,
                                                  u16* __restrict__ vto) {
  __shared__ __align__(16) u16 As[128 * 64];
  __shared__ __align__(16) u16 Bs[128 * 64];
  f32x4 acc[4][4] = {};
  const int m0 = blockIdx.y << 7, n0 = blockIdx.x << 7;
  gemm_core(A, Bt, m0, n0, As, Bs, acc);
  const int tid = threadIdx.x, w = tid >> 6, lane = tid & 63;
  const int wr = w >> 1, wc = w & 1, lr = lane & 15, lg = lane >> 4;
  const int gcb = n0 + (wc << 6);           // 64-aligned column base: one head block
  const int three = gcb >> 10;              // 0=q 1=k 2=v (uniform per wave)
  const int nh = (gcb & 1023) >> 6;
#pragma unroll
  for (int n = 0; n < 4; ++n) {
    const int hd = n * 16 + lr;
    const float bv = bias[gcb + hd];
#pragma unroll
    for (int m = 0; m < 4; ++m) {
#pragma unroll
      for (int r = 0; r < 4; ++r) {
        const int grow = m0 + (wr << 6) + m * 16 + (lg << 2) + r;
        const int bb = grow >> 11, t = grow & 2047;
        const float val = acc[m][n][r] + bv;
        const int head = (bb << 4) + nh;
        if (three == 0)
          qo[((size_t)head * TT + t) * HDIM + hd] = f2bf(val * 0.125f);  // pre-scale 1/sqrt(64)
        else if (three == 1)
          ko[((size_t)head * TT + t) * HDIM + hd] = f2bf(val);
        else
          vto[((size_t)head * HDIM + hd) * TT + t] = f2bf(val);  // V transposed
      }
    }
  }
}

// ---------------- windowed flash attention ----------------
// grid: (T/64, B*NH), 256 thr = 4 waves; wave handles 16 q-rows.
__global__ __launch_bounds__(256) void attn_win_k(const u16* __restrict__ Q,
                                                  const u16* __restrict__ K,
                                                  const u16* __restrict__ Vt,
                                                  u16* __restrict__ O) {
  __shared__ __align__(16) u16 Pl[4][16][40];  // per-wave P tile, padded rows
  const int tid = threadIdx.x, w = tid >> 6, lane = tid & 63;
  const int head = blockIdx.y;
  const int t0w = blockIdx.x * 64 + w * 16;
  const u16* Qh = Q + (size_t)head * TT * HDIM;
  const u16* Kh = K + (size_t)head * TT * HDIM;
  const u16* Vh = Vt + (size_t)head * HDIM * TT;
  const int lr = lane & 15, lg = lane >> 4;

  bf16x8 qa0 = *(const bf16x8*)(Qh + (size_t)(t0w + lr) * HDIM + lg * 8);
  bf16x8 qa1 = *(const bf16x8*)(Qh + (size_t)(t0w + lr) * HDIM + 32 + lg * 8);

  f32x4 o0 = {}, o1 = {}, o2 = {}, o3 = {};
  float m[4], lsum[4];
#pragma unroll
  for (int r = 0; r < 4; ++r) { m[r] = -1e30f; lsum[r] = 0.f; }

  const int jstart = (t0w > 255) ? ((t0w - 255) & ~31) : 0;
  const int jlast = t0w + 15;
  for (int j0 = jstart; j0 <= jlast; j0 += 32) {
    // S = Q K^T (pre-scaled), 16x32 tile in 2 col-frags
    f32x4 s[2];
#pragma unroll
    for (int n = 0; n < 2; ++n) {
      const u16* kp = Kh + (size_t)(j0 + n * 16 + lr) * HDIM + lg * 8;
      f32x4 z = {};
      z = MFMA(qa0, *(const bf16x8*)kp, z);
      z = MFMA(qa1, *(const bf16x8*)(kp + 32), z);
      s[n] = z;
    }
    // mask + row max
    const int row0 = t0w + (lg << 2);
    float tm[4];
#pragma unroll
    for (int r = 0; r < 4; ++r) {
      const int i = row0 + r;
#pragma unroll
      for (int n = 0; n < 2; ++n) {
        const int j = j0 + n * 16 + lr;
        const bool valid = (j <= i) && (i - j < 256);
        s[n][r] = valid ? s[n][r] : -1e30f;
      }
      tm[r] = fmaxf(s[0][r], s[1][r]);
    }
#pragma unroll
    for (int d = 1; d < 16; d <<= 1)
#pragma unroll
      for (int r = 0; r < 4; ++r) tm[r] = fmaxf(tm[r], __shfl_xor(tm[r], d));
    float sc[4], rs[4];
#pragma unroll
    for (int r = 0; r < 4; ++r) {
      const float mn = fmaxf(m[r], tm[r]);
      sc[r] = __expf(m[r] - mn);
      m[r] = mn;
      rs[r] = 0.f;
    }
#pragma unroll
    for (int n = 0; n < 2; ++n)
#pragma unroll
      for (int r = 0; r < 4; ++r) {
        const float p = __expf(s[n][r] - m[r]);
        s[n][r] = p;
        rs[r] += p;
      }
#pragma unroll
    for (int d = 1; d < 16; d <<= 1)
#pragma unroll
      for (int r = 0; r < 4; ++r) rs[r] += __shfl_xor(rs[r], d);
#pragma unroll
    for (int r = 0; r < 4; ++r) {
      lsum[r] = lsum[r] * sc[r] + rs[r];
      o0[r] *= sc[r]; o1[r] *= sc[r]; o2[r] *= sc[r]; o3[r] *= sc[r];
    }
    // P (C-layout) -> LDS -> A-layout bf16 frags
#pragma unroll
    for (int n = 0; n < 2; ++n)
#pragma unroll
      for (int r = 0; r < 4; ++r)
        Pl[w][(lg << 2) + r][n * 16 + lr] = f2bf(s[n][r]);
    asm volatile("s_waitcnt lgkmcnt(0)" ::: "memory");
    bf16x8 pa = *(const bf16x8*)&Pl[w][lr][lg * 8];
    const u16* vp = Vh + (size_t)lr * TT + j0 + lg * 8;
    o0 = MFMA(pa, *(const bf16x8*)(vp), o0);
    o1 = MFMA(pa, *(const bf16x8*)(vp + 16 * TT), o1);
    o2 = MFMA(pa, *(const bf16x8*)(vp + 32 * TT), o2);
    o3 = MFMA(pa, *(const bf16x8*)(vp + 48 * TT), o3);
  }
  const int bb = head >> 4, nh = head & 15;
#pragma unroll
  for (int r = 0; r < 4; ++r) {
    const float inv = 1.0f / lsum[r];
    const int i = t0w + (lg << 2) + r;
    u16* op = O + ((size_t)bb * TT + i) * 1024 + nh * 64 + lr;
    op[0]  = f2bf(o0[r] * inv);
    op[16] = f2bf(o1[r] * inv);
    op[32] = f2bf(o2[r] * inv);
    op[48] = f2bf(o3[r] * inv);
  }
}

// ---------------- GEMM2: out = attn @ Wout + b (f32 out) ----------------
__global__ __launch_bounds__(256) void gemm_out_k(const u16* __restrict__ A,
                                                  const u16* __restrict__ Bt,
                                                  const float* __restrict__ bias,
                                                  float* __restrict__ out) {
  __shared__ __align__(16) u16 As[128 * 64];
  __shared__ __align__(16) u16 Bs[128 * 64];
  f32x4 acc[4][4] = {};
  const int m0 = blockIdx.y << 7, n0 = blockIdx.x << 7;
  gemm_core(A, Bt, m0, n0, As, Bs, acc);
  const int tid = threadIdx.x, w = tid >> 6, lane = tid & 63;
  const int wr = w >> 1, wc = w & 1, lr = lane & 15, lg = lane >> 4;
#pragma unroll
  for (int n = 0; n < 4; ++n) {
    const int gc = n0 + (wc << 6) + n * 16 + lr;
    const float bv = bias[gc];
#pragma unroll
    for (int m = 0; m < 4; ++m)
#pragma unroll
      for (int r = 0; r < 4; ++r) {
        const int grow = m0 + (wr << 6) + m * 16 + (lg << 2) + r;
        out[(size_t)grow * 1024 + gc] = acc[m][n][r] + bv;
      }
  }
}

extern "C" void kernel_launch(void* const* d_in, const int* in_sizes, int n_in,
                              void* d_out, int out_size, void* d_ws, size_t ws_size,
                              hipStream_t stream) {
  (void)in_sizes; (void)n_in; (void)out_size; (void)ws_size;
  const float* x    = (const float*)d_in[0];  // [2,2048,1024]
  const float* Wqkv = (const float*)d_in[1];  // [1024,3072]
  const float* bqkv = (const float*)d_in[2];  // [3072]
  const float* Wout = (const float*)d_in[3];  // [1024,1024]
  const float* bout = (const float*)d_in[4];  // [1024]
  float* out = (float*)d_out;                 // [2,2048,1024] f32

  u16* ws    = (u16*)d_ws;
  u16* xb    = ws;                    // 4194304  x bf16 [4096][1024]
  u16* wqkvT = xb + 4194304;          // 3145728  Wqkv^T bf16 [3072][1024]
  u16* woutT = wqkvT + 3145728;       // 1048576  Wout^T bf16 [1024][1024]
  u16* qb    = woutT + 1048576;       // 4194304  q bf16 [B,NH,T,HD] (pre-scaled)
  u16* kb    = qb + 4194304;          // 4194304  k
  u16* vtb   = kb + 4194304;          // 4194304  v^T [B,NH,HD,T]
  u16* aob   = vtb + 4194304;         // 4194304  attn out bf16 [4096][1024]

  cvt_bf16_k<<<2048, 256, 0, stream>>>(x, xb);
  transpose_cvt_k<<<dim3(3072 / 32, 1024 / 32), 256, 0, stream>>>(Wqkv, wqkvT, 1024, 3072);
  transpose_cvt_k<<<dim3(1024 / 32, 1024 / 32), 256, 0, stream>>>(Wout, woutT, 1024, 1024);
  gemm_qkv_k<<<dim3(24, 32), 256, 0, stream>>>(xb, wqkvT, bqkv, qb, kb, vtb);
  attn_win_k<<<dim3(32, 32), 256, 0, stream>>>(qb, kb, vtb, aob);
  gemm_out_k<<<dim3(8, 32), 256, 0, stream>>>(aob, woutT, bout, out);
}

// Round 3
// 187.759 us; speedup vs baseline: 1.1311x; 1.1311x over previous
//
#include <hip/hip_runtime.h>

typedef unsigned short u16;
typedef __attribute__((ext_vector_type(8))) __bf16 bf16x8;
typedef __attribute__((ext_vector_type(4))) float f32x4;
typedef __attribute__((ext_vector_type(8))) u16 u16x8;

#define MFMA(a, b, c) __builtin_amdgcn_mfma_f32_16x16x32_bf16((a), (b), (c), 0, 0, 0)

// B=2, T=2048, H=1024, NH=16, HD=64, WINDOW=256
#define TT 2048
#define NHEAD 16
#define HDIM 64

__device__ __forceinline__ u16 f2bf(float f) {
  union { float f; unsigned u; } v; v.f = f;
  unsigned r = (v.u + 0x7fffu + ((v.u >> 16) & 1u)) >> 16;
  return (u16)r;
}

__device__ __forceinline__ void gll16(const u16* g, u16* l) {
  __builtin_amdgcn_global_load_lds(
      (__attribute__((address_space(1))) void*)g,
      (__attribute__((address_space(3))) void*)l, 16, 0, 0);
}

// ---------------- f32 -> bf16 convert (x) ----------------
__global__ __launch_bounds__(256) void cvt_bf16_k(const float* __restrict__ in,
                                                  u16* __restrict__ out) {
  int i = blockIdx.x * 256 + threadIdx.x;  // one thread = 8 elems
  float4 a = ((const float4*)in)[2 * i];
  float4 b = ((const float4*)in)[2 * i + 1];
  u16x8 r;
  r[0] = f2bf(a.x); r[1] = f2bf(a.y); r[2] = f2bf(a.z); r[3] = f2bf(a.w);
  r[4] = f2bf(b.x); r[5] = f2bf(b.y); r[6] = f2bf(b.z); r[7] = f2bf(b.w);
  ((u16x8*)out)[i] = r;
}

// ---------------- transpose + convert: in[R][C] f32 -> out[C][R] bf16 ----------------
__global__ __launch_bounds__(256) void transpose_cvt_k(const float* __restrict__ in,
                                                       u16* __restrict__ out,
                                                       int R, int C) {
  __shared__ float tile[32][33];
  int tx = threadIdx.x & 31, ty = threadIdx.x >> 5;  // 32 x 8
  int r0 = blockIdx.y * 32, c0 = blockIdx.x * 32;
#pragma unroll
  for (int i = 0; i < 4; ++i)
    tile[ty + i * 8][tx] = in[(size_t)(r0 + ty + i * 8) * C + c0 + tx];
  __syncthreads();
#pragma unroll
  for (int i = 0; i < 4; ++i)
    out[(size_t)(c0 + ty + i * 8) * R + r0 + tx] = f2bf(tile[tx][ty + i * 8]);
}

// ---------------- GEMM core: C[128x128] += A[128xK] * Bt[128xK]^T, K=1024, BK=32 ----------------
// A row-major [M][1024] bf16, Bt row-major [N][1024] bf16 (i.e. B transposed).
// 256 threads = 4 waves in 2x2; each wave does 64x64 via 4x4 16x16x32 MFMA frags.
// BK=32 -> LDS rows are 64B: ds_read_b128 across the wave touches 8 distinct rows
// per bank = exactly the 8-cycle minimum (conflict-free). BK=64's 128B rows were a
// 16-way conflict (bank independent of row) -- 9.4M conflict cycles in R1.
__device__ __forceinline__ void gemm_core(const u16* __restrict__ A,
                                          const u16* __restrict__ Bt,
                                          int m0, int n0,
                                          u16* As, u16* Bs, f32x4 acc[4][4]) {
  const int tid = threadIdx.x;
  const int w = tid >> 6, lane = tid & 63;
  const int wr = w >> 1, wc = w & 1;
  const int lr = lane & 15, lk = (lane >> 4) << 3;
  const int srow = w << 5;  // each wave stages 32 rows of each tile
  const u16* ga = A + (size_t)(m0 + srow + (lane >> 2)) * 1024 + ((lane & 3) << 3);
  const u16* gb = Bt + (size_t)(n0 + srow + (lane >> 2)) * 1024 + ((lane & 3) << 3);
  u16* la = As + srow * 32;
  u16* lb = Bs + srow * 32;
  for (int k0 = 0; k0 < 1024; k0 += 32) {
#pragma unroll
    for (int i = 0; i < 2; ++i) {
      gll16(ga + i * 16384 + k0, la + i * 512);  // 16 rows (x1024 elems) per gll16
      gll16(gb + i * 16384 + k0, lb + i * 512);
    }
    __syncthreads();
    bf16x8 af[4], bfr[4];
#pragma unroll
    for (int m = 0; m < 4; ++m)
      af[m] = *(const bf16x8*)(As + ((wr << 6) + m * 16 + lr) * 32 + lk);
#pragma unroll
    for (int n = 0; n < 4; ++n)
      bfr[n] = *(const bf16x8*)(Bs + ((wc << 6) + n * 16 + lr) * 32 + lk);
#pragma unroll
    for (int m = 0; m < 4; ++m)
#pragma unroll
      for (int n = 0; n < 4; ++n)
        acc[m][n] = MFMA(af[m], bfr[n], acc[m][n]);
    __syncthreads();
  }
}

// ---------------- GEMM1: qkv = x @ Wqkv + b, scatter to q/k/vT bf16 ----------------
__global__ __launch_bounds__(256) void gemm_qkv_k(const u16* __restrict__ A,
                                                  const u16* __restrict__ Bt,
                                                  const float* __restrict__ bias,
                                                  u16* __restrict__ qo,
                                                  u16* __restrict__ ko,
                                                  u16* __restrict__ vto) {
  __shared__ __align__(16) u16 As[128 * 32];
  __shared__ __align__(16) u16 Bs[128 * 32];
  f32x4 acc[4][4] = {};
  const int m0 = blockIdx.y << 7, n0 = blockIdx.x << 7;
  gemm_core(A, Bt, m0, n0, As, Bs, acc);
  const int tid = threadIdx.x, w = tid >> 6, lane = tid & 63;
  const int wr = w >> 1, wc = w & 1, lr = lane & 15, lg = lane >> 4;
  const int gcb = n0 + (wc << 6);           // 64-aligned column base: one head block
  const int three = gcb >> 10;              // 0=q 1=k 2=v (uniform per wave)
  const int nh = (gcb & 1023) >> 6;
#pragma unroll
  for (int n = 0; n < 4; ++n) {
    const int hd = n * 16 + lr;
    const float bv = bias[gcb + hd];
#pragma unroll
    for (int m = 0; m < 4; ++m) {
#pragma unroll
      for (int r = 0; r < 4; ++r) {
        const int grow = m0 + (wr << 6) + m * 16 + (lg << 2) + r;
        const int bb = grow >> 11, t = grow & 2047;
        const float val = acc[m][n][r] + bv;
        const int head = (bb << 4) + nh;
        if (three == 0)
          qo[((size_t)head * TT + t) * HDIM + hd] = f2bf(val * 0.125f);  // pre-scale 1/sqrt(64)
        else if (three == 1)
          ko[((size_t)head * TT + t) * HDIM + hd] = f2bf(val);
        else
          vto[((size_t)head * HDIM + hd) * TT + t] = f2bf(val);  // V transposed
      }
    }
  }
}

// ---------------- windowed flash attention ----------------
// grid: (T/64, B*NH), 256 thr = 4 waves; wave handles 16 q-rows.
__global__ __launch_bounds__(256) void attn_win_k(const u16* __restrict__ Q,
                                                  const u16* __restrict__ K,
                                                  const u16* __restrict__ Vt,
                                                  u16* __restrict__ O) {
  __shared__ __align__(16) u16 Pl[4][16][40];  // per-wave P tile, padded rows
  const int tid = threadIdx.x, w = tid >> 6, lane = tid & 63;
  const int head = blockIdx.y;
  const int t0w = blockIdx.x * 64 + w * 16;
  const u16* Qh = Q + (size_t)head * TT * HDIM;
  const u16* Kh = K + (size_t)head * TT * HDIM;
  const u16* Vh = Vt + (size_t)head * HDIM * TT;
  const int lr = lane & 15, lg = lane >> 4;

  bf16x8 qa0 = *(const bf16x8*)(Qh + (size_t)(t0w + lr) * HDIM + lg * 8);
  bf16x8 qa1 = *(const bf16x8*)(Qh + (size_t)(t0w + lr) * HDIM + 32 + lg * 8);

  f32x4 o0 = {}, o1 = {}, o2 = {}, o3 = {};
  float m[4], lsum[4];
#pragma unroll
  for (int r = 0; r < 4; ++r) { m[r] = -1e30f; lsum[r] = 0.f; }

  const int jstart = (t0w > 255) ? ((t0w - 255) & ~31) : 0;
  const int jlast = t0w + 15;
  for (int j0 = jstart; j0 <= jlast; j0 += 32) {
    // S = Q K^T (pre-scaled), 16x32 tile in 2 col-frags
    f32x4 s[2];
#pragma unroll
    for (int n = 0; n < 2; ++n) {
      const u16* kp = Kh + (size_t)(j0 + n * 16 + lr) * HDIM + lg * 8;
      f32x4 z = {};
      z = MFMA(qa0, *(const bf16x8*)kp, z);
      z = MFMA(qa1, *(const bf16x8*)(kp + 32), z);
      s[n] = z;
    }
    // mask + row max
    const int row0 = t0w + (lg << 2);
    float tm[4];
#pragma unroll
    for (int r = 0; r < 4; ++r) {
      const int i = row0 + r;
#pragma unroll
      for (int n = 0; n < 2; ++n) {
        const int j = j0 + n * 16 + lr;
        const bool valid = (j <= i) && (i - j < 256);
        s[n][r] = valid ? s[n][r] : -1e30f;
      }
      tm[r] = fmaxf(s[0][r], s[1][r]);
    }
#pragma unroll
    for (int d = 1; d < 16; d <<= 1)
#pragma unroll
      for (int r = 0; r < 4; ++r) tm[r] = fmaxf(tm[r], __shfl_xor(tm[r], d));
    float sc[4], rs[4];
#pragma unroll
    for (int r = 0; r < 4; ++r) {
      const float mn = fmaxf(m[r], tm[r]);
      sc[r] = __expf(m[r] - mn);
      m[r] = mn;
      rs[r] = 0.f;
    }
#pragma unroll
    for (int n = 0; n < 2; ++n)
#pragma unroll
      for (int r = 0; r < 4; ++r) {
        const float p = __expf(s[n][r] - m[r]);
        s[n][r] = p;
        rs[r] += p;
      }
#pragma unroll
    for (int d = 1; d < 16; d <<= 1)
#pragma unroll
      for (int r = 0; r < 4; ++r) rs[r] += __shfl_xor(rs[r], d);
#pragma unroll
    for (int r = 0; r < 4; ++r) {
      lsum[r] = lsum[r] * sc[r] + rs[r];
      o0[r] *= sc[r]; o1[r] *= sc[r]; o2[r] *= sc[r]; o3[r] *= sc[r];
    }
    // P (C-layout) -> LDS -> A-layout bf16 frags
#pragma unroll
    for (int n = 0; n < 2; ++n)
#pragma unroll
      for (int r = 0; r < 4; ++r)
        Pl[w][(lg << 2) + r][n * 16 + lr] = f2bf(s[n][r]);
    asm volatile("s_waitcnt lgkmcnt(0)" ::: "memory");
    bf16x8 pa = *(const bf16x8*)&Pl[w][lr][lg * 8];
    const u16* vp = Vh + (size_t)lr * TT + j0 + lg * 8;
    o0 = MFMA(pa, *(const bf16x8*)(vp), o0);
    o1 = MFMA(pa, *(const bf16x8*)(vp + 16 * TT), o1);
    o2 = MFMA(pa, *(const bf16x8*)(vp + 32 * TT), o2);
    o3 = MFMA(pa, *(const bf16x8*)(vp + 48 * TT), o3);
  }
  const int bb = head >> 4, nh = head & 15;
#pragma unroll
  for (int r = 0; r < 4; ++r) {
    const float inv = 1.0f / lsum[r];
    const int i = t0w + (lg << 2) + r;
    u16* op = O + ((size_t)bb * TT + i) * 1024 + nh * 64 + lr;
    op[0]  = f2bf(o0[r] * inv);
    op[16] = f2bf(o1[r] * inv);
    op[32] = f2bf(o2[r] * inv);
    op[48] = f2bf(o3[r] * inv);
  }
}

// ---------------- GEMM2: out = attn @ Wout + b (f32 out) ----------------
__global__ __launch_bounds__(256) void gemm_out_k(const u16* __restrict__ A,
                                                  const u16* __restrict__ Bt,
                                                  const float* __restrict__ bias,
                                                  float* __restrict__ out) {
  __shared__ __align__(16) u16 As[128 * 32];
  __shared__ __align__(16) u16 Bs[128 * 32];
  f32x4 acc[4][4] = {};
  const int m0 = blockIdx.y << 7, n0 = blockIdx.x << 7;
  gemm_core(A, Bt, m0, n0, As, Bs, acc);
  const int tid = threadIdx.x, w = tid >> 6, lane = tid & 63;
  const int wr = w >> 1, wc = w & 1, lr = lane & 15, lg = lane >> 4;
#pragma unroll
  for (int n = 0; n < 4; ++n) {
    const int gc = n0 + (wc << 6) + n * 16 + lr;
    const float bv = bias[gc];
#pragma unroll
    for (int m = 0; m < 4; ++m)
#pragma unroll
      for (int r = 0; r < 4; ++r) {
        const int grow = m0 + (wr << 6) + m * 16 + (lg << 2) + r;
        out[(size_t)grow * 1024 + gc] = acc[m][n][r] + bv;
      }
  }
}

extern "C" void kernel_launch(void* const* d_in, const int* in_sizes, int n_in,
                              void* d_out, int out_size, void* d_ws, size_t ws_size,
                              hipStream_t stream) {
  (void)in_sizes; (void)n_in; (void)out_size; (void)ws_size;
  const float* x    = (const float*)d_in[0];  // [2,2048,1024]
  const float* Wqkv = (const float*)d_in[1];  // [1024,3072]
  const float* bqkv = (const float*)d_in[2];  // [3072]
  const float* Wout = (const float*)d_in[3];  // [1024,1024]
  const float* bout = (const float*)d_in[4];  // [1024]
  float* out = (float*)d_out;                 // [2,2048,1024] f32

  u16* ws    = (u16*)d_ws;
  u16* xb    = ws;                    // 4194304  x bf16 [4096][1024]
  u16* wqkvT = xb + 4194304;          // 3145728  Wqkv^T bf16 [3072][1024]
  u16* woutT = wqkvT + 3145728;       // 1048576  Wout^T bf16 [1024][1024]
  u16* qb    = woutT + 1048576;       // 4194304  q bf16 [B,NH,T,HD] (pre-scaled)
  u16* kb    = qb + 4194304;          // 4194304  k
  u16* vtb   = kb + 4194304;          // 4194304  v^T [B,NH,HD,T]
  u16* aob   = vtb + 4194304;         // 4194304  attn out bf16 [4096][1024]

  cvt_bf16_k<<<2048, 256, 0, stream>>>(x, xb);
  transpose_cvt_k<<<dim3(3072 / 32, 1024 / 32), 256, 0, stream>>>(Wqkv, wqkvT, 1024, 3072);
  transpose_cvt_k<<<dim3(1024 / 32, 1024 / 32), 256, 0, stream>>>(Wout, woutT, 1024, 1024);
  gemm_qkv_k<<<dim3(24, 32), 256, 0, stream>>>(xb, wqkvT, bqkv, qb, kb, vtb);
  attn_win_k<<<dim3(32, 32), 256, 0, stream>>>(qb, kb, vtb, aob);
  gemm_out_k<<<dim3(8, 32), 256, 0, stream>>>(aob, woutT, bout, out);
}